// Round 5
// baseline (212.093 us; speedup 1.0000x reference)
//
#include <hip/hip_runtime.h>
#include <math.h>

#define AN 4096
#define CN 8
#define FN 64
#define ACN (AN*CN)   // 32768

typedef __attribute__((ext_vector_type(8))) short bf16x8;
typedef __attribute__((ext_vector_type(4))) float f32x4;

__device__ inline unsigned short f2bf(float f) {
    unsigned u = __float_as_uint(f);
    unsigned r = ((u >> 16) & 1) + 0x7FFFu;   // round-to-nearest-even
    return (unsigned short)((u + r) >> 16);
}

// ---------------------------------------------------------------------------
// K1: normalize scales + bf16 matrix.
//   xnb bf16 [c][a][f]  (MFMA operand source), sc fp32 [a*8+c] (1/clamped-norm)
// ---------------------------------------------------------------------------
__global__ __launch_bounds__(256) void k1_normalize(const float* __restrict__ x,
                                                    unsigned short* __restrict__ xnb,
                                                    float* __restrict__ sc)
{
    int tid  = threadIdx.x;
    int grp  = tid >> 4;
    int slot = tid & 15;
    int V = blockIdx.x * 16 + grp;          // a*8+c
    const float4 v = *(const float4*)(x + (size_t)V * FN + slot * 4);
    float ss = v.x*v.x + v.y*v.y + v.z*v.z + v.w*v.w;
    ss += __shfl_xor(ss, 1);
    ss += __shfl_xor(ss, 2);
    ss += __shfl_xor(ss, 4);
    ss += __shfl_xor(ss, 8);
    float s = 1.0f / fmaxf(sqrtf(ss), 1e-6f);
    if (slot == 0) sc[V] = s;
    ushort4 ob;
    ob.x = f2bf(v.x * s); ob.y = f2bf(v.y * s);
    ob.z = f2bf(v.z * s); ob.w = f2bf(v.w * s);
    int a = V >> 3, c = V & 7;
    *(ushort4*)(xnb + ((size_t)c * AN + a) * FN + slot * 4) = ob;
}

// ---------------------------------------------------------------------------
// K2: MFMA sim + slim packed argmax. 4 blocks/CU for latency hiding.
// Grid 1024 = 8c x 32 row-tiles x 4 col-quarters; 256 thr = 4 waves (2x2
// quads, 64x64 each); 8 col-iterations of 128 over this quarter's 1024 cols.
// A fragments loaded DIRECTLY from global once (L2-resident, no LDS) — LDS
// holds only the B double-buffer (32 KB) + reduce (1 KB) = 33 KB -> 4
// blocks/CU; VGPR capped at 128 via __launch_bounds__(256,4) -> 16 waves/CU.
// (R4 was grid-limited to 2 blocks/CU = 25% occupancy; barrier drains had
// no co-resident waves to overlap with -> MfmaUtil 12%.)
// Packed argmax: acc init 2.0 (s'=2+sim in [1,3]); in-loop pack carries only
// it*128|ni*16 (bits 4-9); quarter*1024|wc*64|l15 (bits 10-11,6,0-3) OR'd
// once post-loop. Diagonal: single scalar-branched iteration (it==sdit).
// ---------------------------------------------------------------------------
__global__ __launch_bounds__(256, 4) void k2_argmax(const unsigned short* __restrict__ xnb,
                                                    unsigned int* __restrict__ pP)
{
    __shared__ uint4 lds4[2 * 1024];   // Bt0 | Bt1 (32 KB)
    __shared__ float red[4][64];

    int blk  = blockIdx.x;
    int qtr  = blk & 3;
    int rt   = (blk >> 2) & 31;
    int c    = blk >> 7;
    int a0   = rt * 128;
    int q0   = qtr * 1024;

    int tid  = threadIdx.x;
    int lane = tid & 63;
    int w    = tid >> 6;
    int wr   = w >> 1;
    int wc   = w & 1;
    int l15  = lane & 15;
    int quad = lane >> 4;

    const uint4* __restrict__ Xc4 = (const uint4*)(xnb + (size_t)c * AN * FN);
    const bf16x8* __restrict__ X8 = (const bf16x8*)Xc4;

    int srow   = tid >> 3;    // 0..31
    int schunk = tid & 7;     // 0..7

    // ---- stage B tile 0 into LDS buffer 0 ----
    #pragma unroll
    for (int s = 0; s < 4; ++s) {
        int r = srow + 32 * s;
        lds4[r * 8 + (schunk ^ (r & 7))] = Xc4[(size_t)(q0 + r) * 8 + schunk];
    }

    // ---- A fragments straight from global (loop-invariant, L2-resident) ----
    int arow = a0 + wr * 64 + l15;
    bf16x8 afr[4][2];
    #pragma unroll
    for (int mi = 0; mi < 4; ++mi)
        #pragma unroll
        for (int ks = 0; ks < 2; ++ks)
            afr[mi][ks] = X8[(size_t)(arow + mi * 16) * 8 + ks * 4 + quad];

    // ---- diagonal iteration for this wave (or -1) ----
    int rel  = (a0 + wr * 64) - q0;
    int dit  = ((unsigned)rel < 1024u && (((rel >> 6) & 1) == wc)) ? (rel >> 7) : -1;
    int sdit = __builtin_amdgcn_readfirstlane(dit);

    float bestp[16];
    #pragma unroll
    for (int i = 0; i < 16; ++i) bestp[i] = 0.0f;

    const f32x4 two = {2.0f, 2.0f, 2.0f, 2.0f};
    __syncthreads();

    #pragma unroll 2
    for (int it = 0; it < 8; ++it) {
        int cur = it & 1;

        // prefetch next B tile into registers
        uint4 gv[4];
        if (it < 7) {
            int g0 = q0 + (it + 1) * 128;
            #pragma unroll
            for (int s = 0; s < 4; ++s)
                gv[s] = Xc4[(size_t)(g0 + srow + 32 * s) * 8 + schunk];
        }

        // ---- B fragments from LDS, MFMA ----
        const bf16x8* bt = (const bf16x8*)(lds4 + cur * 1024);
        bf16x8 bfr[2][4];
        #pragma unroll
        for (int ks = 0; ks < 2; ++ks)
            #pragma unroll
            for (int ni = 0; ni < 4; ++ni) {
                int r  = wc * 64 + ni * 16 + l15;
                int ch = (ks * 4 + quad) ^ (r & 7);
                bfr[ks][ni] = bt[r * 8 + ch];
            }

        f32x4 acc[4][4];
        #pragma unroll
        for (int ni = 0; ni < 4; ++ni)
            #pragma unroll
            for (int mi = 0; mi < 4; ++mi) {
                acc[mi][ni] = __builtin_amdgcn_mfma_f32_16x16x32_bf16(afr[mi][0], bfr[0][ni], two, 0, 0, 0);
                acc[mi][ni] = __builtin_amdgcn_mfma_f32_16x16x32_bf16(afr[mi][1], bfr[1][ni], acc[mi][ni], 0, 0, 0);
            }

        // ---- diagonal patch (one iteration per affected wave) ----
        if (it == sdit) {
            #pragma unroll
            for (int mi = 0; mi < 4; ++mi)
                #pragma unroll
                for (int rr = 0; rr < 4; ++rr)
                    if (l15 == quad * 4 + rr) acc[mi][mi][rr] = -2.0f;
        }

        // ---- slim packed argmax: 1 and_or + max tree per element ----
        #pragma unroll
        for (int mi = 0; mi < 4; ++mi)
            #pragma unroll
            for (int rr = 0; rr < 4; ++rr) {
                unsigned p0 = (__float_as_uint(acc[mi][0][rr]) & 0xFFFFF000u) | (unsigned)(it * 128);
                unsigned p1 = (__float_as_uint(acc[mi][1][rr]) & 0xFFFFF000u) | (unsigned)(it * 128 + 16);
                unsigned p2 = (__float_as_uint(acc[mi][2][rr]) & 0xFFFFF000u) | (unsigned)(it * 128 + 32);
                unsigned p3 = (__float_as_uint(acc[mi][3][rr]) & 0xFFFFF000u) | (unsigned)(it * 128 + 48);
                float m01 = fmaxf(__uint_as_float(p0), __uint_as_float(p1));
                float m23 = fmaxf(__uint_as_float(p2), __uint_as_float(p3));
                bestp[mi * 4 + rr] = fmaxf(bestp[mi * 4 + rr], fmaxf(m01, m23));
            }

        // ---- write prefetched tile into other buffer ----
        if (it < 7) {
            #pragma unroll
            for (int s = 0; s < 4; ++s) {
                int r = srow + 32 * s;
                lds4[(cur ^ 1) * 1024 + r * 8 + (schunk ^ (r & 7))] = gv[s];
            }
        }
        __syncthreads();
    }

    // ---- OR in the lane/wave-constant column bits, then reduce ----
    unsigned tailcode = (unsigned)(q0 + wc * 64 + l15);
    #pragma unroll
    for (int i = 0; i < 16; ++i) {
        float v = __uint_as_float(__float_as_uint(bestp[i]) | tailcode);
        v = fmaxf(v, __shfl_xor(v, 1));
        v = fmaxf(v, __shfl_xor(v, 2));
        v = fmaxf(v, __shfl_xor(v, 4));
        v = fmaxf(v, __shfl_xor(v, 8));
        bestp[i] = v;
    }
    if (l15 == 0) {
        #pragma unroll
        for (int mi = 0; mi < 4; ++mi)
            #pragma unroll
            for (int rr = 0; rr < 4; ++rr)
                red[w][mi * 16 + quad * 4 + rr] = bestp[mi * 4 + rr];
    }
    __syncthreads();
    if (tid < 128) {
        int wr2 = tid >> 6, r64 = tid & 63;
        float p = fmaxf(red[wr2 * 2][r64], red[wr2 * 2 + 1][r64]);
        int a = a0 + wr2 * 64 + r64;
        pP[(size_t)qtr * ACN + (size_t)a * CN + c] = __float_as_uint(p);
    }
}

// ---------------------------------------------------------------------------
// K3: merge 4 quarters, unpack index, exact fp32 distance (x*sc) + log, reduce.
// ---------------------------------------------------------------------------
__global__ __launch_bounds__(256) void k3_dist(const float* __restrict__ x,
                                               const float* __restrict__ sc,
                                               const unsigned int* __restrict__ pP,
                                               float* __restrict__ partials)
{
    int id = blockIdx.x * 256 + threadIdx.x;   // a*8 + c
    float p0 = __uint_as_float(pP[id]);
    float p1 = __uint_as_float(pP[ACN + id]);
    float p2 = __uint_as_float(pP[2 * ACN + id]);
    float p3 = __uint_as_float(pP[3 * ACN + id]);
    unsigned pm = __float_as_uint(fmaxf(fmaxf(p0, p1), fmaxf(p2, p3)));
    int m = (int)(pm & 0xFFFu);
    int c = id & 7;
    int jb = m * CN + c;
    float sa = sc[id], sb = sc[jb];
    const float* xa = x + (size_t)id * FN;
    const float* xb = x + (size_t)jb * FN;
    float ss = 0.0f;
    #pragma unroll
    for (int q = 0; q < 16; ++q) {
        float4 va = *(const float4*)(xa + 4 * q);
        float4 vb = *(const float4*)(xb + 4 * q);
        float d0 = va.x * sa - vb.x * sb + 1e-6f;
        float d1 = va.y * sa - vb.y * sb + 1e-6f;
        float d2 = va.z * sa - vb.z * sb + 1e-6f;
        float d3 = va.w * sa - vb.w * sb + 1e-6f;
        ss += d0*d0 + d1*d1 + d2*d2 + d3*d3;
    }
    float val = logf(sqrtf(ss) + 1e-6f);

    float t = val;
    #pragma unroll
    for (int off = 32; off > 0; off >>= 1) t += __shfl_down(t, off);
    __shared__ float ws4[4];
    if ((threadIdx.x & 63) == 0) ws4[threadIdx.x >> 6] = t;
    __syncthreads();
    if (threadIdx.x == 0)
        partials[blockIdx.x] = ws4[0] + ws4[1] + ws4[2] + ws4[3];
}

// ---------------------------------------------------------------------------
// K4: out = -sum(partials)/32768
// ---------------------------------------------------------------------------
__global__ __launch_bounds__(64) void k4_final(const float* __restrict__ partials,
                                               float* __restrict__ out)
{
    int t = threadIdx.x;
    float v = partials[t] + partials[t + 64];
    #pragma unroll
    for (int off = 32; off > 0; off >>= 1) v += __shfl_down(v, off);
    if (t == 0) out[0] = -v / (float)ACN;
}

extern "C" void kernel_launch(void* const* d_in, const int* in_sizes, int n_in,
                              void* d_out, int out_size, void* d_ws, size_t ws_size,
                              hipStream_t stream)
{
    const float* x = (const float*)d_in[0];
    unsigned short* xnb = (unsigned short*)d_ws;                 // 4 MB bf16 [c][a][f]
    float* sc = (float*)(xnb + (size_t)AN * CN * FN);            // 32768 floats
    unsigned int* pP = (unsigned int*)(sc + ACN);                // 4*32768 uints
    float* partials = (float*)(pP + 4 * ACN);                    // 128 floats

    k1_normalize<<<2048, 256, 0, stream>>>(x, xnb, sc);
    k2_argmax  <<<1024, 256, 0, stream>>>(xnb, pP);
    k3_dist    <<<128, 256, 0, stream>>>(x, sc, pP, partials);
    k4_final   <<<1, 64, 0, stream>>>(partials, (float*)d_out);
}

// Round 6
// 112.468 us; speedup vs baseline: 1.8858x; 1.8858x over previous
//
#include <hip/hip_runtime.h>
#include <math.h>

#define AN 4096
#define CN 8
#define FN 64
#define ACN (AN*CN)   // 32768

typedef __attribute__((ext_vector_type(8))) short bf16x8;
typedef __attribute__((ext_vector_type(4))) float f32x4;

__device__ inline unsigned short f2bf(float f) {
    unsigned u = __float_as_uint(f);
    unsigned r = ((u >> 16) & 1) + 0x7FFFu;   // round-to-nearest-even
    return (unsigned short)((u + r) >> 16);
}

// ---------------------------------------------------------------------------
// K1: normalize scales + bf16 matrix.
//   xnb bf16 [c][a][f]  (MFMA operand source), sc fp32 [a*8+c] (1/clamped-norm)
// ---------------------------------------------------------------------------
__global__ __launch_bounds__(256) void k1_normalize(const float* __restrict__ x,
                                                    unsigned short* __restrict__ xnb,
                                                    float* __restrict__ sc)
{
    int tid  = threadIdx.x;
    int grp  = tid >> 4;
    int slot = tid & 15;
    int V = blockIdx.x * 16 + grp;          // a*8+c
    const float4 v = *(const float4*)(x + (size_t)V * FN + slot * 4);
    float ss = v.x*v.x + v.y*v.y + v.z*v.z + v.w*v.w;
    ss += __shfl_xor(ss, 1);
    ss += __shfl_xor(ss, 2);
    ss += __shfl_xor(ss, 4);
    ss += __shfl_xor(ss, 8);
    float s = 1.0f / fmaxf(sqrtf(ss), 1e-6f);
    if (slot == 0) sc[V] = s;
    ushort4 ob;
    ob.x = f2bf(v.x * s); ob.y = f2bf(v.y * s);
    ob.z = f2bf(v.z * s); ob.w = f2bf(v.w * s);
    int a = V >> 3, c = V & 7;
    *(ushort4*)(xnb + ((size_t)c * AN + a) * FN + slot * 4) = ob;
}

// ---------------------------------------------------------------------------
// K2: MFMA sim + slim packed argmax, small wave tile for real occupancy.
// Grid 1024 = 8c x 32 row-tiles x 4 col-quarters; 256 thr = 4 waves stacked
// by ROWS: wave w owns rows [a0+w*32, a0+w*32+32), all waves share cols.
// 16 iterations of 64 cols over this quarter's 1024 cols.
// Wave tile 32x64: acc = 8 f32x4 (32 AGPR), afr 16, bestp 8 regs — R5 spilled
// because 64 acc AGPRs + ~110 live VGPRs can't fit 4 waves/EU in the unified
// 512-reg file; this tile fits ~135 total -> 3-4 waves/SIMD without forcing.
// B double-buffered in LDS (2 x 8 KB, staged cooperatively, reused by all 4
// waves); A frags direct from global (L2-resident). One barrier per iter.
// Waves own disjoint rows -> final argmax written straight from registers
// (no cross-wave LDS reduce).
// Packed argmax: acc init 2.0 (s'=2+sim in [1,3]); in-loop pack carries
// it*64|ni*16 (bits 4-9); q0|l15 (bits 10-11, 0-3) OR'd once post-loop.
// Diagonal: single scalar-branched iteration (it==sdit), nbase wave-uniform.
// ---------------------------------------------------------------------------
__global__ __launch_bounds__(256, 2) void k2_argmax(const unsigned short* __restrict__ xnb,
                                                    unsigned int* __restrict__ pP)
{
    __shared__ uint4 lds4[2 * 512];   // Bt0 | Bt1 (16 KB), 64 rows x 8 chunks each

    int blk  = blockIdx.x;
    int qtr  = blk & 3;
    int rt   = (blk >> 2) & 31;
    int c    = blk >> 7;
    int a0   = rt * 128;
    int q0   = qtr * 1024;

    int tid  = threadIdx.x;
    int lane = tid & 63;
    int w    = tid >> 6;        // wave id 0..3 = row block
    int l15  = lane & 15;
    int quad = lane >> 4;

    const uint4* __restrict__ Xc4 = (const uint4*)(xnb + (size_t)c * AN * FN);
    const bf16x8* __restrict__ X8 = (const bf16x8*)Xc4;

    int sr  = tid >> 3;   // 0..31 (staging row base; rows sr, sr+32)
    int sch = tid & 7;    // chunk 0..7

    // ---- stage B tile 0 into buffer 0 ----
    #pragma unroll
    for (int s = 0; s < 2; ++s) {
        int r = sr + 32 * s;
        lds4[r * 8 + (sch ^ (r & 7))] = Xc4[(size_t)(q0 + r) * 8 + sch];
    }

    // ---- A fragments straight from global (loop-invariant, L2-resident) ----
    int arow = a0 + w * 32 + l15;
    bf16x8 afr[2][2];
    #pragma unroll
    for (int mi = 0; mi < 2; ++mi)
        #pragma unroll
        for (int ks = 0; ks < 2; ++ks)
            afr[mi][ks] = X8[(size_t)(arow + mi * 16) * 8 + ks * 4 + quad];

    // ---- diagonal iteration + ni base for this wave (wave-uniform) ----
    int rel   = (a0 + w * 32) - q0;                       // multiple of 32
    int dit   = ((unsigned)rel < 1024u) ? (rel >> 6) : -1;
    int sdit  = __builtin_amdgcn_readfirstlane(dit);
    int nbase = __builtin_amdgcn_readfirstlane((rel >> 4) & 2);   // 0 or 2

    float bestp[8];
    #pragma unroll
    for (int i = 0; i < 8; ++i) bestp[i] = 0.0f;

    const f32x4 two = {2.0f, 2.0f, 2.0f, 2.0f};
    __syncthreads();

    #pragma unroll 2
    for (int it = 0; it < 16; ++it) {
        int cur = it & 1;

        // prefetch next B tile into registers (2 uint4/thread)
        uint4 gv[2];
        if (it < 15) {
            int g0 = q0 + (it + 1) * 64;
            #pragma unroll
            for (int s = 0; s < 2; ++s)
                gv[s] = Xc4[(size_t)(g0 + sr + 32 * s) * 8 + sch];
        }

        // ---- B fragments from LDS (shared by all 4 waves), MFMA ----
        const bf16x8* bt = (const bf16x8*)(lds4 + cur * 512);
        bf16x8 bfr[2][4];
        #pragma unroll
        for (int ks = 0; ks < 2; ++ks)
            #pragma unroll
            for (int ni = 0; ni < 4; ++ni) {
                int r  = ni * 16 + l15;
                int ch = (ks * 4 + quad) ^ (r & 7);
                bfr[ks][ni] = bt[r * 8 + ch];
            }

        f32x4 acc[2][4];
        #pragma unroll
        for (int ni = 0; ni < 4; ++ni)
            #pragma unroll
            for (int mi = 0; mi < 2; ++mi) {
                acc[mi][ni] = __builtin_amdgcn_mfma_f32_16x16x32_bf16(afr[mi][0], bfr[0][ni], two, 0, 0, 0);
                acc[mi][ni] = __builtin_amdgcn_mfma_f32_16x16x32_bf16(afr[mi][1], bfr[1][ni], acc[mi][ni], 0, 0, 0);
            }

        // ---- diagonal patch (one iteration per wave) ----
        if (it == sdit) {
            #pragma unroll
            for (int mi = 0; mi < 2; ++mi)
                #pragma unroll
                for (int rr = 0; rr < 4; ++rr)
                    if (l15 == quad * 4 + rr) acc[mi][nbase + mi][rr] = -2.0f;
        }

        // ---- packed argmax: 4 and_or + 2 max3 per 4 elements ----
        #pragma unroll
        for (int mi = 0; mi < 2; ++mi)
            #pragma unroll
            for (int rr = 0; rr < 4; ++rr) {
                unsigned p0 = (__float_as_uint(acc[mi][0][rr]) & 0xFFFFF000u) | (unsigned)(it * 64);
                unsigned p1 = (__float_as_uint(acc[mi][1][rr]) & 0xFFFFF000u) | (unsigned)(it * 64 + 16);
                unsigned p2 = (__float_as_uint(acc[mi][2][rr]) & 0xFFFFF000u) | (unsigned)(it * 64 + 32);
                unsigned p3 = (__float_as_uint(acc[mi][3][rr]) & 0xFFFFF000u) | (unsigned)(it * 64 + 48);
                float m0 = fmaxf(fmaxf(__uint_as_float(p0), __uint_as_float(p1)), __uint_as_float(p2));
                bestp[mi * 4 + rr] = fmaxf(fmaxf(m0, __uint_as_float(p3)), bestp[mi * 4 + rr]);
            }

        // ---- write prefetched tile into other buffer ----
        if (it < 15) {
            #pragma unroll
            for (int s = 0; s < 2; ++s) {
                int r = sr + 32 * s;
                lds4[(cur ^ 1) * 512 + r * 8 + (sch ^ (r & 7))] = gv[s];
            }
        }
        __syncthreads();
    }

    // ---- OR in constant column bits, reduce across 16 col-lanes, store ----
    unsigned tailcode = (unsigned)(q0 + l15);
    #pragma unroll
    for (int i = 0; i < 8; ++i) {
        float v = __uint_as_float(__float_as_uint(bestp[i]) | tailcode);
        v = fmaxf(v, __shfl_xor(v, 1));
        v = fmaxf(v, __shfl_xor(v, 2));
        v = fmaxf(v, __shfl_xor(v, 4));
        v = fmaxf(v, __shfl_xor(v, 8));
        bestp[i] = v;
    }
    // lanes with l15==0 (one per quad) hold results for rows mi*16+quad*4+rr
    if (l15 == 0) {
        #pragma unroll
        for (int mi = 0; mi < 2; ++mi)
            #pragma unroll
            for (int rr = 0; rr < 4; ++rr) {
                int a = a0 + w * 32 + mi * 16 + quad * 4 + rr;
                pP[(size_t)qtr * ACN + (size_t)a * CN + c] = __float_as_uint(bestp[mi * 4 + rr]);
            }
    }
}

// ---------------------------------------------------------------------------
// K3: merge 4 quarters, unpack index, exact fp32 distance (x*sc) + log, reduce.
// ---------------------------------------------------------------------------
__global__ __launch_bounds__(256) void k3_dist(const float* __restrict__ x,
                                               const float* __restrict__ sc,
                                               const unsigned int* __restrict__ pP,
                                               float* __restrict__ partials)
{
    int id = blockIdx.x * 256 + threadIdx.x;   // a*8 + c
    float p0 = __uint_as_float(pP[id]);
    float p1 = __uint_as_float(pP[ACN + id]);
    float p2 = __uint_as_float(pP[2 * ACN + id]);
    float p3 = __uint_as_float(pP[3 * ACN + id]);
    unsigned pm = __float_as_uint(fmaxf(fmaxf(p0, p1), fmaxf(p2, p3)));
    int m = (int)(pm & 0xFFFu);
    int c = id & 7;
    int jb = m * CN + c;
    float sa = sc[id], sb = sc[jb];
    const float* xa = x + (size_t)id * FN;
    const float* xb = x + (size_t)jb * FN;
    float ss = 0.0f;
    #pragma unroll
    for (int q = 0; q < 16; ++q) {
        float4 va = *(const float4*)(xa + 4 * q);
        float4 vb = *(const float4*)(xb + 4 * q);
        float d0 = va.x * sa - vb.x * sb + 1e-6f;
        float d1 = va.y * sa - vb.y * sb + 1e-6f;
        float d2 = va.z * sa - vb.z * sb + 1e-6f;
        float d3 = va.w * sa - vb.w * sb + 1e-6f;
        ss += d0*d0 + d1*d1 + d2*d2 + d3*d3;
    }
    float val = logf(sqrtf(ss) + 1e-6f);

    float t = val;
    #pragma unroll
    for (int off = 32; off > 0; off >>= 1) t += __shfl_down(t, off);
    __shared__ float ws4[4];
    if ((threadIdx.x & 63) == 0) ws4[threadIdx.x >> 6] = t;
    __syncthreads();
    if (threadIdx.x == 0)
        partials[blockIdx.x] = ws4[0] + ws4[1] + ws4[2] + ws4[3];
}

// ---------------------------------------------------------------------------
// K4: out = -sum(partials)/32768
// ---------------------------------------------------------------------------
__global__ __launch_bounds__(64) void k4_final(const float* __restrict__ partials,
                                               float* __restrict__ out)
{
    int t = threadIdx.x;
    float v = partials[t] + partials[t + 64];
    #pragma unroll
    for (int off = 32; off > 0; off >>= 1) v += __shfl_down(v, off);
    if (t == 0) out[0] = -v / (float)ACN;
}

extern "C" void kernel_launch(void* const* d_in, const int* in_sizes, int n_in,
                              void* d_out, int out_size, void* d_ws, size_t ws_size,
                              hipStream_t stream)
{
    const float* x = (const float*)d_in[0];
    unsigned short* xnb = (unsigned short*)d_ws;                 // 4 MB bf16 [c][a][f]
    float* sc = (float*)(xnb + (size_t)AN * CN * FN);            // 32768 floats
    unsigned int* pP = (unsigned int*)(sc + ACN);                // 4*32768 uints
    float* partials = (float*)(pP + 4 * ACN);                    // 128 floats

    k1_normalize<<<2048, 256, 0, stream>>>(x, xnb, sc);
    k2_argmax  <<<1024, 256, 0, stream>>>(xnb, pP);
    k3_dist    <<<128, 256, 0, stream>>>(x, sc, pP, partials);
    k4_final   <<<1, 64, 0, stream>>>(partials, (float*)d_out);
}